// Round 5
// baseline (301.693 us; speedup 1.0000x reference)
//
#include <hip/hip_runtime.h>
#include <stdint.h>

// Calibration-histogram kernel for MI355X.
// probs: (1,2,4096,4096) f32, labels: (1,1,4096,4096) i32.
// Outputs (flat, 90 f32): count0[15], csum0[15], asum0[15], count1[15], csum1[15], asum1[15].
//
// Strategy: memory-bound streaming pass. Per pixel per channel we do ONE
// packed ds_add_u64 into a per-16-lane-group LDS sub-histogram:
//   [63:32] = round(conf * 2^18)   (csum, fixed point)
//   [31:16] = (label == ch)        (asum)
//   [15:0]  = 1                    (count)
// Bounds: <=512 pixels per sub-histogram bucket -> count<=2^9, csum<=2^27,
// so no cross-field carry. Final merge: unpack, global float atomicAdd.

#define NBINS 15

__global__ void zero_out_kernel(float* out, int n) {
    int i = blockIdx.x * blockDim.x + threadIdx.x;
    if (i < n) out[i] = 0.0f;
}

__device__ __forceinline__ void bin_one(unsigned long long* h, float c, int match) {
    // Reference: bin i holds conf in (b[i], b[i+1]]; conf==0 -> invalid.
    if (c > 0.0f && c <= 1.0f) {
        int bin = (int)(c * 15.0f);
        bin = bin > 14 ? 14 : bin;
        unsigned int cf = __float2uint_rn(c * 262144.0f);   // conf * 2^18, <= 2^18
        unsigned long long v = ((unsigned long long)cf << 32)
                             | ((unsigned long long)(match ? 1u : 0u) << 16)
                             | 1ull;
        atomicAdd(&h[bin], v);
    }
}

__global__ __launch_bounds__(256) void calib_hist_kernel(
        const float* __restrict__ probs, const int* __restrict__ labels,
        float* __restrict__ out, int npix) {
    // 16 sub-histograms per block (one per 16-lane group), each 2ch x 16 bins.
    // Stride 33 u64 (264 B) between groups -> bank rotation, no systematic
    // cross-group bank conflict.
    __shared__ unsigned long long hist[16 * 33];
    int tid = threadIdx.x;
    for (int i = tid; i < 16 * 33; i += 256) hist[i] = 0ull;
    __syncthreads();

    unsigned long long* h = &hist[(tid >> 4) * 33];  // (wave<<2)|grp == tid>>4

    const float4* p0 = (const float4*)probs;          // channel 0
    const float4* p1 = (const float4*)(probs + npix); // channel 1
    const int4*   lb = (const int4*)labels;
    int nvec   = npix >> 2;
    int stride = gridDim.x * blockDim.x;
    for (int i = blockIdx.x * blockDim.x + tid; i < nvec; i += stride) {
        float4 a = p0[i];
        float4 b = p1[i];
        int4   l = lb[i];
        bin_one(h,      a.x, l.x == 0);
        bin_one(h + 16, b.x, l.x == 1);
        bin_one(h,      a.y, l.y == 0);
        bin_one(h + 16, b.y, l.y == 1);
        bin_one(h,      a.z, l.z == 0);
        bin_one(h + 16, b.z, l.z == 1);
        bin_one(h,      a.w, l.w == 0);
        bin_one(h + 16, b.w, l.w == 1);
    }
    __syncthreads();

    // Merge the block's 16 sub-histograms, unpack, and accumulate globally.
    if (tid < 2 * NBINS) {
        int ch = tid / NBINS, bin = tid % NBINS;
        unsigned long long cnt = 0, asum = 0, csum = 0;
        for (int wg = 0; wg < 16; ++wg) {
            unsigned long long x = hist[wg * 33 + ch * 16 + bin];
            cnt  += x & 0xFFFFull;
            asum += (x >> 16) & 0xFFFFull;
            csum += x >> 32;
        }
        float* base = out + ch * 45;
        atomicAdd(base + bin,            (float)cnt);
        atomicAdd(base + NBINS + bin,    (float)csum * (1.0f / 262144.0f));
        atomicAdd(base + 2 * NBINS + bin,(float)asum);
    }
}

extern "C" void kernel_launch(void* const* d_in, const int* in_sizes, int n_in,
                              void* d_out, int out_size, void* d_ws, size_t ws_size,
                              hipStream_t stream) {
    const float* probs  = (const float*)d_in[0];
    const int*   labels = (const int*)d_in[1];
    float*       out    = (float*)d_out;
    int npix = in_sizes[1];  // 4096*4096 pixels; probs has 2*npix elements

    zero_out_kernel<<<(out_size + 127) / 128, 128, 0, stream>>>(out, out_size);

    // 2048 blocks x 256 threads: 8 blocks/CU -> 32 waves/CU, grid-stride.
    calib_hist_kernel<<<2048, 256, 0, stream>>>(probs, labels, out, npix);
}

// Round 7
// 258.134 us; speedup vs baseline: 1.1687x; 1.1687x over previous
//
#include <hip/hip_runtime.h>
#include <stdint.h>

// Calibration-histogram kernel for MI355X (round 6).
// probs: (1,2,4096,4096) f32, labels: (1,1,4096,4096) i32.
// Outputs (flat, 90 f32): count0[15], csum0[15], asum0[15], count1[15], csum1[15], asum1[15].
//
// Round-5 post-mortem: ds_add_u64 LDS atomics cost ~164 cyc/wave-instr
// (per-lane RMW serialization) -> 140 us, 9% HBM. Fix: per-LANE private
// histograms in LDS with plain (non-atomic) u64 read-add-write.
//   hist[e][tid], e = ch*16 + bin, 32 x 256 u64 = 64 KB/block.
//   bank(byte = e*2048 + tid*8) = 2*tid mod 32  -> independent of bin,
//   every 64-lane b64 op touches each bank exactly 4x = conflict-free min.
// Packed per-thread accumulator:
//   [63:32] = round(conf * 2^18)  (csum fixed-point)
//   [31:16] = (label == ch)       (asum)
//   [15:0]  = 1                   (count)
// 512 blocks x 256 thr -> 32 iters/thread -> <=128 updates per thread-bin:
// count<=2^7, asum<=2^7, csum<=2^25 -> no cross-field carry.

#define NBINS 15

__global__ void zero_out_kernel(float* out, int n) {
    int i = blockIdx.x * blockDim.x + threadIdx.x;
    if (i < n) out[i] = 0.0f;
}

__device__ __forceinline__ unsigned long long pack_update(float c, int match, int* bin_out) {
    // Reference: bin i holds conf in (b[i], b[i+1]]; conf==0 -> invalid.
    bool valid = (c > 0.0f) && (c <= 1.0f);
    float cb = fmaxf(fminf(c * 15.0f, 14.0f), 0.0f);   // clamped bin, branchless
    *bin_out = (int)cb;
    unsigned int cf = __float2uint_rn(fmaxf(c, 0.0f) * 262144.0f);  // conf * 2^18 (exact scale)
    unsigned long long v = ((unsigned long long)cf << 32)
                         | ((unsigned long long)(match ? 1u : 0u) << 16)
                         | 1ull;
    return valid ? v : 0ull;   // invalid -> add zero (keeps control flow uniform)
}

__global__ __launch_bounds__(256) void calib_hist_kernel(
        const float* __restrict__ probs, const int* __restrict__ labels,
        float* __restrict__ out, int npix) {
    __shared__ unsigned long long hist[32 * 256];   // [e][tid], 64 KB
    int tid = threadIdx.x;
    #pragma unroll
    for (int k = 0; k < 32; ++k) hist[k * 256 + tid] = 0ull;  // bank-clean init
    __syncthreads();

    const float4* p0 = (const float4*)probs;           // channel 0
    const float4* p1 = (const float4*)(probs + npix);  // channel 1
    const int4*   lb = (const int4*)labels;
    int nvec   = npix >> 2;
    int stride = gridDim.x * blockDim.x;

    for (int i = blockIdx.x * blockDim.x + tid; i < nvec; i += stride) {
        float4 a = p0[i];
        float4 b = p1[i];
        int4   l = lb[i];
        int bin;
        unsigned long long v;
        // Sequential non-atomic RMW: each lane owns column tid -> no cross-lane
        // races; in-source order protects within-thread same-bin collisions.
        v = pack_update(a.x, l.x == 0, &bin); hist[bin * 256 + tid] += v;
        v = pack_update(b.x, l.x == 1, &bin); hist[(16 + bin) * 256 + tid] += v;
        v = pack_update(a.y, l.y == 0, &bin); hist[bin * 256 + tid] += v;
        v = pack_update(b.y, l.y == 1, &bin); hist[(16 + bin) * 256 + tid] += v;
        v = pack_update(a.z, l.z == 0, &bin); hist[bin * 256 + tid] += v;
        v = pack_update(b.z, l.z == 1, &bin); hist[(16 + bin) * 256 + tid] += v;
        v = pack_update(a.w, l.w == 0, &bin); hist[bin * 256 + tid] += v;
        v = pack_update(b.w, l.w == 1, &bin); hist[(16 + bin) * 256 + tid] += v;
    }
    __syncthreads();

    // Merge: 32 lanes, lane e sums its 256 columns with rotated start
    // (t = (it + e) & 255 -> 2 touches/bank, conflict-free).
    if (tid < 32) {
        int e = tid;
        unsigned long long cnt = 0, asum = 0, csum = 0;
        for (int it = 0; it < 256; ++it) {
            int t = (it + e) & 255;
            unsigned long long x = hist[e * 256 + t];
            cnt  += x & 0xFFFFull;
            asum += (x >> 16) & 0xFFFFull;
            csum += x >> 32;
        }
        int ch = e >> 4, bin = e & 15;
        if (bin < NBINS) {
            float* base = out + ch * 45;
            atomicAdd(base + bin,             (float)cnt);
            atomicAdd(base + NBINS + bin,     (float)csum * (1.0f / 262144.0f));
            atomicAdd(base + 2 * NBINS + bin, (float)asum);
        }
    }
}

extern "C" void kernel_launch(void* const* d_in, const int* in_sizes, int n_in,
                              void* d_out, int out_size, void* d_ws, size_t ws_size,
                              hipStream_t stream) {
    const float* probs  = (const float*)d_in[0];
    const int*   labels = (const int*)d_in[1];
    float*       out    = (float*)d_out;
    int npix = in_sizes[1];  // 4096*4096 pixels; probs has 2*npix elements

    zero_out_kernel<<<(out_size + 127) / 128, 128, 0, stream>>>(out, out_size);

    // Cap iterations/thread at 32 so packed fields can't carry:
    // 512 blocks for npix=16.7M; 64 KB LDS -> 2 blocks/CU resident.
    int nvec = npix >> 2;
    int blocks = (nvec + 256 * 32 - 1) / (256 * 32);
    if (blocks < 1) blocks = 1;
    calib_hist_kernel<<<blocks, 256, 0, stream>>>(probs, labels, out, npix);
}